// Round 8
// baseline (105.539 us; speedup 1.0000x reference)
//
#include <hip/hip_runtime.h>
#include <math.h>

#define BATCH 4096
#define DIM 128
#define NCLS 100
#define MARGIN 0.3f
#define NTILE 544          // upper-triangle 64x256 tiles
#define GRID_MAIN 800      // 544 pairwise + 256 CE

typedef __attribute__((ext_vector_type(8))) short short8;
typedef __attribute__((ext_vector_type(4))) float f32x4;

// ---- bf16 helpers (bit-level, RNE) ----
__device__ __forceinline__ unsigned short f2bf(float f) {
    unsigned int u = __float_as_uint(f);
    unsigned int r = (u + 0x7FFFu + ((u >> 16) & 1u)) >> 16;
    return (unsigned short)r;
}
__device__ __forceinline__ float bf2f(unsigned short b) {
    return __uint_as_float(((unsigned int)b) << 16);
}

// Order-preserving encodings for NONNEGATIVE floats; identity = 0 under atomic max.
#define ENC_MAX_ID 0x80000000u   /* enc_max(0.0f) */
#define ENC_MIN_ID 0x403FFFFFu   /* enc_min(+inf) */
__device__ __forceinline__ unsigned int enc_max(float v) {
    return (__float_as_uint(v) >> 1) | 0x80000000u;
}
__device__ __forceinline__ float dec_max(unsigned int k) {
    return __uint_as_float((k & 0x7FFFFFFFu) << 1);
}
__device__ __forceinline__ unsigned int enc_min(float v) {
    return 0x7FFFFFFFu - (__float_as_uint(v) >> 1);
}
__device__ __forceinline__ float dec_min(unsigned int k) {
    return __uint_as_float((0x7FFFFFFFu - k) << 1);
}

// K1: blocks 0..255: emb->bf16 + sq (from rounded values so diag d2==0).
//     blocks 256..257: fc_w->bf16 (padded to 112 classes) + zero fan-in region.
__global__ __launch_bounds__(256) void prep_kernel(
        const float* __restrict__ emb, const float* __restrict__ fcw,
        unsigned short* __restrict__ ebf, float* __restrict__ sq,
        unsigned short* __restrict__ wbf, unsigned int* __restrict__ fanz) {
    int bid = blockIdx.x, tid = threadIdx.x;
    if (bid < 256) {
        int wave = tid >> 6, lane = tid & 63;
        #pragma unroll
        for (int r = 0; r < 4; ++r) {
            int row = bid * 16 + wave * 4 + r;
            const float2* src = reinterpret_cast<const float2*>(emb + row * DIM);
            float2 xy = src[lane];
            unsigned short b0 = f2bf(xy.x), b1 = f2bf(xy.y);
            float y0 = bf2f(b0), y1 = bf2f(b1);
            reinterpret_cast<unsigned int*>(ebf + row * DIM)[lane] =
                ((unsigned int)b1 << 16) | (unsigned int)b0;
            float acc = y0 * y0 + y1 * y1;
            #pragma unroll
            for (int off = 1; off < 64; off <<= 1) acc += __shfl_xor(acc, off, 64);
            if (lane == 0) sq[row] = acc;
        }
    } else {
        int idx = (bid - 256) * 256 + tid;          // 512 threads total
        for (int k = idx; k < 112 * DIM; k += 512)
            wbf[k] = (k < NCLS * DIM) ? f2bf(fcw[k]) : (unsigned short)0;
        for (int w = idx; w < 8194; w += 512)       // ticket+ce_sum+maxk+mink
            fanz[w] = 0;
    }
}

// K2: blocks 0..543  -> upper-triangle pairwise tiles (64 rows x 256 cols),
//                       SOFTWARE-PIPELINED ct loop (prefetch ct+1 during ct);
//     blocks 544..799 -> CE per 16 rows via MFMA logits + wave softmax.
//     Fence-free encoded-atomic fan-in; last block reduces + writes out[0].
__global__ __launch_bounds__(256) void main_kernel(
        const unsigned short* __restrict__ ebf, const unsigned short* __restrict__ wbf,
        const float* __restrict__ sq, const int* __restrict__ labels,
        const float* __restrict__ fcb,
        unsigned int* __restrict__ maxk, unsigned int* __restrict__ mink,
        float* __restrict__ ce_sum, int* __restrict__ ticket,
        float* __restrict__ out) {
    __shared__ float lg[16][128];
    __shared__ unsigned int colk[512];   // [0..255] col-max keys, [256..511] col-min keys
    __shared__ int lastFlag;
    int bid = blockIdx.x, tid = threadIdx.x;
    int wave = tid >> 6, lane = tid & 63;
    int lm = lane & 15, lq = lane >> 4;
    int koff = lq * 8;                 // frag: [idx=lane&15][k = lq*8 + j]

    if (bid < NTILE) {
        // ---- map bid -> (rowgrp, chunk) in the upper triangle ----
        int q = 0, rem = bid;
        while (rem >= 4 * (16 - q)) { rem -= 4 * (16 - q); ++q; }
        int cpr = 16 - q;
        int sub = rem / cpr, coff = rem % cpr;
        int rowgrp = 4 * q + sub;
        int chunk  = q + coff;

        int rbase = rowgrp * 64 + wave * 16;
        int arow = rbase + lm;
        const unsigned short* apt = ebf + arow * DIM + koff;
        short8 a0 = *reinterpret_cast<const short8*>(apt);
        short8 a1 = *reinterpret_cast<const short8*>(apt + 32);
        short8 a2 = *reinterpret_cast<const short8*>(apt + 64);
        short8 a3 = *reinterpret_cast<const short8*>(apt + 96);

        int labr[4];
        float sqr[4];
        #pragma unroll
        for (int r = 0; r < 4; ++r) {
            labr[r] = labels[rbase + lq * 4 + r];
            sqr[r]  = sq[rbase + lq * 4 + r];
        }

        colk[tid] = 0; colk[256 + tid] = 0;
        __syncthreads();

        float rmax[4] = {-INFINITY, -INFINITY, -INFINITY, -INFINITY};
        float rmin[4] = { INFINITY,  INFINITY,  INFINITY,  INFINITY};

        int cbase = chunk * 256;
        int col0 = cbase + lm;
        const unsigned short* bp0 = ebf + col0 * DIM + koff;

        // ---- software pipeline: preload ct=0 ----
        short8 cb0 = *reinterpret_cast<const short8*>(bp0);
        short8 cb1 = *reinterpret_cast<const short8*>(bp0 + 32);
        short8 cb2 = *reinterpret_cast<const short8*>(bp0 + 64);
        short8 cb3 = *reinterpret_cast<const short8*>(bp0 + 96);
        float csq = sq[col0];
        int   clc = labels[col0];

        #pragma unroll 2
        for (int ct = 0; ct < 16; ++ct) {
            // prefetch ct+1 BEFORE consuming ct (hides L2 latency behind compute)
            short8 nb0, nb1, nb2, nb3;
            float nsq = 0.f; int nlc = 0;
            if (ct < 15) {
                const unsigned short* np = bp0 + (ct + 1) * 16 * DIM;
                nb0 = *reinterpret_cast<const short8*>(np);
                nb1 = *reinterpret_cast<const short8*>(np + 32);
                nb2 = *reinterpret_cast<const short8*>(np + 64);
                nb3 = *reinterpret_cast<const short8*>(np + 96);
                nsq = sq[col0 + (ct + 1) * 16];
                nlc = labels[col0 + (ct + 1) * 16];
            }

            f32x4 c = {0.f, 0.f, 0.f, 0.f};
            c = __builtin_amdgcn_mfma_f32_16x16x32_bf16(a0, cb0, c, 0, 0, 0);
            c = __builtin_amdgcn_mfma_f32_16x16x32_bf16(a1, cb1, c, 0, 0, 0);
            c = __builtin_amdgcn_mfma_f32_16x16x32_bf16(a2, cb2, c, 0, 0, 0);
            c = __builtin_amdgcn_mfma_f32_16x16x32_bf16(a3, cb3, c, 0, 0, 0);

            float cmax = -INFINITY, cmin = INFINITY;
            #pragma unroll
            for (int r = 0; r < 4; ++r) {
                float v = fmaxf(fmaf(c[r], -2.0f, csq) + sqr[r], 0.f);  // d^2 >= 0
                bool same = (clc == labr[r]);
                rmax[r] = same ? fmaxf(rmax[r], v) : rmax[r];
                rmin[r] = same ? rmin[r] : fminf(rmin[r], v);
                cmax    = same ? fmaxf(cmax, v) : cmax;
                cmin    = same ? cmin : fminf(cmin, v);
            }
            // fold this wave's 16 rows into the 16 cols (combine lq groups)
            cmax = fmaxf(cmax, __shfl_xor(cmax, 16, 64));
            cmax = fmaxf(cmax, __shfl_xor(cmax, 32, 64));
            cmin = fminf(cmin, __shfl_xor(cmin, 16, 64));
            cmin = fminf(cmin, __shfl_xor(cmin, 32, 64));
            if (lq == 0) {   // 16 lanes, 16 distinct banks -> conflict-free ds atomics
                atomicMax(&colk[ct * 16 + lm], enc_max(fmaxf(cmax, 0.f)));
                atomicMax(&colk[256 + ct * 16 + lm], enc_min(fmaxf(cmin, 0.f)));
            }

            // rotate
            cb0 = nb0; cb1 = nb1; cb2 = nb2; cb3 = nb3;
            csq = nsq; clc = nlc;
        }
        // row reduce across the 16 col-slots
        #pragma unroll
        for (int off = 1; off < 16; off <<= 1) {
            #pragma unroll
            for (int r = 0; r < 4; ++r) {
                rmax[r] = fmaxf(rmax[r], __shfl_xor(rmax[r], off, 64));
                rmin[r] = fminf(rmin[r], __shfl_xor(rmin[r], off, 64));
            }
        }
        if (lm == 0) {
            int row0 = rbase + lq * 4;
            #pragma unroll
            for (int r = 0; r < 4; ++r) {
                unsigned int kx = enc_max(fmaxf(rmax[r], 0.f));
                unsigned int kn = enc_min(fmaxf(rmin[r], 0.f));
                if (kx != ENC_MAX_ID)
                    __hip_atomic_fetch_max(&maxk[row0 + r], kx,
                                           __ATOMIC_RELAXED, __HIP_MEMORY_SCOPE_AGENT);
                if (kn != ENC_MIN_ID)
                    __hip_atomic_fetch_max(&mink[row0 + r], kn,
                                           __ATOMIC_RELAXED, __HIP_MEMORY_SCOPE_AGENT);
            }
        }
        __syncthreads();
        // column publish: one thread per col
        {
            unsigned int kx = colk[tid], kn = colk[256 + tid];
            int col = cbase + tid;
            if (kx > ENC_MAX_ID)       // >: skip identity AND the harmless enc_max(0)
                __hip_atomic_fetch_max(&maxk[col], kx,
                                       __ATOMIC_RELAXED, __HIP_MEMORY_SCOPE_AGENT);
            if (kn != 0 && kn != ENC_MIN_ID)
                __hip_atomic_fetch_max(&mink[col], kn,
                                       __ATOMIC_RELAXED, __HIP_MEMORY_SCOPE_AGENT);
        }
    } else {
        // ---------------- cross-entropy ----------------
        int R0 = (bid - NTILE) * 16;
        lg[tid >> 4][112 + (tid & 15)] = -INFINITY;   // pad cols 112..127

        int arow = R0 + lm;
        const unsigned short* apt = ebf + arow * DIM + koff;
        short8 a0 = *reinterpret_cast<const short8*>(apt);
        short8 a1 = *reinterpret_cast<const short8*>(apt + 32);
        short8 a2 = *reinterpret_cast<const short8*>(apt + 64);
        short8 a3 = *reinterpret_cast<const short8*>(apt + 96);

        for (int t = wave * 2; t < 7 && t < wave * 2 + 2; ++t) {
            int cls = t * 16 + lm;
            const unsigned short* bp = wbf + cls * DIM + koff;
            short8 b0 = *reinterpret_cast<const short8*>(bp);
            short8 b1 = *reinterpret_cast<const short8*>(bp + 32);
            short8 b2 = *reinterpret_cast<const short8*>(bp + 64);
            short8 b3 = *reinterpret_cast<const short8*>(bp + 96);
            f32x4 c = {0.f, 0.f, 0.f, 0.f};
            c = __builtin_amdgcn_mfma_f32_16x16x32_bf16(a0, b0, c, 0, 0, 0);
            c = __builtin_amdgcn_mfma_f32_16x16x32_bf16(a1, b1, c, 0, 0, 0);
            c = __builtin_amdgcn_mfma_f32_16x16x32_bf16(a2, b2, c, 0, 0, 0);
            c = __builtin_amdgcn_mfma_f32_16x16x32_bf16(a3, b3, c, 0, 0, 0);
            float bias = (cls < NCLS) ? fcb[cls] : -INFINITY;
            #pragma unroll
            for (int r = 0; r < 4; ++r)
                lg[lq * 4 + r][t * 16 + lm] = c[r] + bias;
        }
        __syncthreads();
        float cacc = 0.f;
        #pragma unroll
        for (int i = 0; i < 4; ++i) {
            int r = wave * 4 + i;
            float x0 = lg[r][lane], x1 = lg[r][lane + 64];
            float m = fmaxf(x0, x1);
            #pragma unroll
            for (int off = 1; off < 64; off <<= 1) m = fmaxf(m, __shfl_xor(m, off, 64));
            float s = expf(x0 - m) + expf(x1 - m);    // -inf pads -> 0
            #pragma unroll
            for (int off = 1; off < 64; off <<= 1) s += __shfl_xor(s, off, 64);
            if (lane == 0) {
                int lab = labels[R0 + r];
                cacc += (m + logf(s)) - lg[r][lab];
            }
        }
        __syncthreads();
        if (lane == 0) lg[0][wave] = cacc;
        __syncthreads();
        if (tid == 0) {
            float bsum = lg[0][0] + lg[0][1] + lg[0][2] + lg[0][3];
            __hip_atomic_fetch_add(ce_sum, bsum,
                                   __ATOMIC_RELAXED, __HIP_MEMORY_SCOPE_AGENT);
        }
    }

    // ------- fence-free ticket fan-in -------
    __syncthreads();
    asm volatile("s_waitcnt vmcnt(0)" ::: "memory");
    if (tid == 0) {
        int old = __hip_atomic_fetch_add(ticket, 1,
                                         __ATOMIC_RELAXED, __HIP_MEMORY_SCOPE_AGENT);
        lastFlag = (old == GRID_MAIN - 1);
    }
    __syncthreads();
    if (lastFlag) {
        float acc = 0.f;
        #pragma unroll
        for (int rr = 0; rr < 16; ++rr) {
            int row = rr * 256 + tid;
            unsigned int kx = __hip_atomic_load(&maxk[row], __ATOMIC_RELAXED,
                                                __HIP_MEMORY_SCOPE_AGENT);
            unsigned int kn = __hip_atomic_load(&mink[row], __ATOMIC_RELAXED,
                                                __HIP_MEMORY_SCOPE_AGENT);
            float ap = sqrtf(fmaxf(dec_max(kx), 1e-12f));
            float an = sqrtf(fmaxf(dec_min(kn), 1e-12f));
            acc += fmaxf(ap - an + MARGIN, 0.f);
        }
        float* red = reinterpret_cast<float*>(lg);
        red[tid] = acc;
        __syncthreads();
        for (int s = 128; s > 0; s >>= 1) {
            if (tid < s) red[tid] += red[tid + s];
            __syncthreads();
        }
        if (tid == 0) {
            float ces = __hip_atomic_load(ce_sum, __ATOMIC_RELAXED,
                                          __HIP_MEMORY_SCOPE_AGENT);
            out[0] = (red[0] + ces) * (1.0f / BATCH);
        }
    }
}

extern "C" void kernel_launch(void* const* d_in, const int* in_sizes, int n_in,
                              void* d_out, int out_size, void* d_ws, size_t ws_size,
                              hipStream_t stream) {
    const float* emb    = (const float*)d_in[0];
    const int*   labels = (const int*)  d_in[1];
    const float* fcw    = (const float*)d_in[2];
    const float* fcb    = (const float*)d_in[3];
    float* out = (float*)d_out;

    char* ws = (char*)d_ws;
    unsigned short* ebf = (unsigned short*)(ws);                 // 1 MB
    unsigned short* wbf = (unsigned short*)(ws + 1048576);       // 28 KB (pad 32K)
    float* sq           = (float*)(ws + 1081344);                // 16 KB
    char* fan           = ws + 1097728;                          // zeroed by prep
    int*   ticket       = (int*)(fan);                           // 4 B
    float* ce_sum       = (float*)(fan + 4);                     // 4 B
    unsigned int* maxk  = (unsigned int*)(fan + 8);              // 16 KB
    unsigned int* mink  = (unsigned int*)(fan + 8 + 16384);      // 16 KB

    prep_kernel<<<258, 256, 0, stream>>>(emb, fcw, ebf, sq, wbf,
                                         (unsigned int*)fan);
    main_kernel<<<GRID_MAIN, 256, 0, stream>>>(ebf, wbf, sq, labels, fcb,
                                               maxk, mink, ce_sum, ticket, out);
}

// Round 9
// 95.374 us; speedup vs baseline: 1.1066x; 1.1066x over previous
//
#include <hip/hip_runtime.h>
#include <math.h>

#define BATCH 4096
#define DIM 128
#define NCLS 100
#define MARGIN 0.3f
#define NTILE 544          // upper-triangle 64x256 tiles
#define GRID_MAIN 800      // 544 pairwise + 256 CE

typedef __attribute__((ext_vector_type(8))) short short8;
typedef __attribute__((ext_vector_type(4))) float f32x4;

// ---- bf16 helpers (bit-level, RNE) ----
__device__ __forceinline__ unsigned short f2bf(float f) {
    unsigned int u = __float_as_uint(f);
    unsigned int r = (u + 0x7FFFu + ((u >> 16) & 1u)) >> 16;
    return (unsigned short)r;
}
__device__ __forceinline__ float bf2f(unsigned short b) {
    return __uint_as_float(((unsigned int)b) << 16);
}

// Order-preserving encodings for NONNEGATIVE floats; identity = 0 under atomic max.
#define ENC_MAX_ID 0x80000000u   /* enc_max(0.0f) */
#define ENC_MIN_ID 0x403FFFFFu   /* enc_min(+inf) */
__device__ __forceinline__ unsigned int enc_max(float v) {
    return (__float_as_uint(v) >> 1) | 0x80000000u;
}
__device__ __forceinline__ float dec_max(unsigned int k) {
    return __uint_as_float((k & 0x7FFFFFFFu) << 1);
}
__device__ __forceinline__ unsigned int enc_min(float v) {
    return 0x7FFFFFFFu - (__float_as_uint(v) >> 1);
}
__device__ __forceinline__ float dec_min(unsigned int k) {
    return __uint_as_float((0x7FFFFFFFu - k) << 1);
}

// FRAGMENT-MAJOR layout (R9): for 16-row group g, dim-chunk c (=dim/8),
// element (row%16, dim%8) lives at short-index  g*2048 + c*128 + (row%16)*8 + dim%8.
// MFMA fragment read j (dims lq*8+32j..+8) for lanes (lq,lm) then becomes
// contiguous:  addr = g*2048 + j*512 + lane*8 shorts = base + lane*16 bytes.

// K1: blocks 0..255: emb->bf16 (frag-major) + sq (from rounded values).
//     blocks 256..257: fc_w->bf16 frag-major (padded to 112 classes) + zero fan-in.
__global__ __launch_bounds__(256) void prep_kernel(
        const float* __restrict__ emb, const float* __restrict__ fcw,
        unsigned short* __restrict__ ebf, float* __restrict__ sq,
        unsigned short* __restrict__ wbf, unsigned int* __restrict__ fanz) {
    int bid = blockIdx.x, tid = threadIdx.x;
    if (bid < 256) {
        int wave = tid >> 6, lane = tid & 63;
        unsigned int* dstg = reinterpret_cast<unsigned int*>(ebf) + bid * 1024;
        #pragma unroll
        for (int r = 0; r < 4; ++r) {
            int rowl = wave * 4 + r;                 // row within group (0..15)
            int row = bid * 16 + rowl;
            const float2* src = reinterpret_cast<const float2*>(emb + row * DIM);
            float2 xy = src[lane];                   // dims 2*lane, 2*lane+1
            unsigned short b0 = f2bf(xy.x), b1 = f2bf(xy.y);
            float y0 = bf2f(b0), y1 = bf2f(b1);
            // dim pair index = lane: chunk c = lane>>2, pos = (lane&3)*2
            dstg[(lane >> 2) * 64 + rowl * 4 + (lane & 3)] =
                ((unsigned int)b1 << 16) | (unsigned int)b0;
            float acc = y0 * y0 + y1 * y1;
            #pragma unroll
            for (int off = 1; off < 64; off <<= 1) acc += __shfl_xor(acc, off, 64);
            if (lane == 0) sq[row] = acc;
        }
    } else {
        int idx = (bid - 256) * 256 + tid;          // 512 threads total
        for (int k = idx; k < 112 * DIM; k += 512) {
            int cls = k >> 7, d = k & 127;
            int dst = (cls >> 4) * 2048 + (d >> 3) * 128 + (cls & 15) * 8 + (d & 7);
            wbf[dst] = (k < NCLS * DIM) ? f2bf(fcw[k]) : (unsigned short)0;
        }
        for (int w = idx; w < 8194; w += 512)       // ticket+ce_sum+maxk+mink
            fanz[w] = 0;
    }
}

// K2: blocks 0..543  -> upper-triangle pairwise tiles (64 rows x 256 cols);
//                       frag-major loads are base+lane*16B (fully coalesced);
//     blocks 544..799 -> CE per 16 rows via MFMA logits + wave softmax.
//     Fence-free encoded-atomic fan-in; last block reduces + writes out[0].
__global__ __launch_bounds__(256) void main_kernel(
        const unsigned short* __restrict__ ebf, const unsigned short* __restrict__ wbf,
        const float* __restrict__ sq, const int* __restrict__ labels,
        const float* __restrict__ fcb,
        unsigned int* __restrict__ maxk, unsigned int* __restrict__ mink,
        float* __restrict__ ce_sum, int* __restrict__ ticket,
        float* __restrict__ out) {
    __shared__ float lg[16][128];
    __shared__ unsigned int colk[512];   // [0..255] col-max keys, [256..511] col-min keys
    __shared__ int lastFlag;
    int bid = blockIdx.x, tid = threadIdx.x;
    int wave = tid >> 6, lane = tid & 63;
    int lm = lane & 15, lq = lane >> 4;

    if (bid < NTILE) {
        // ---- map bid -> (rowgrp, chunk) in the upper triangle ----
        int q = 0, rem = bid;
        while (rem >= 4 * (16 - q)) { rem -= 4 * (16 - q); ++q; }
        int cpr = 16 - q;
        int sub = rem / cpr, coff = rem % cpr;
        int rowgrp = 4 * q + sub;
        int chunk  = q + coff;

        int rbase = rowgrp * 64 + wave * 16;
        // A-frags: group g_A = rbase/16, contiguous 4KB, lane-coalesced
        const unsigned short* apt = ebf + (rbase >> 4) * 2048 + lane * 8;
        short8 a0 = *reinterpret_cast<const short8*>(apt);
        short8 a1 = *reinterpret_cast<const short8*>(apt + 512);
        short8 a2 = *reinterpret_cast<const short8*>(apt + 1024);
        short8 a3 = *reinterpret_cast<const short8*>(apt + 1536);

        int labr[4];
        float sqr[4];
        #pragma unroll
        for (int r = 0; r < 4; ++r) {
            labr[r] = labels[rbase + lq * 4 + r];
            sqr[r]  = sq[rbase + lq * 4 + r];
        }

        colk[tid] = 0; colk[256 + tid] = 0;
        __syncthreads();

        float rmax[4] = {-INFINITY, -INFINITY, -INFINITY, -INFINITY};
        float rmin[4] = { INFINITY,  INFINITY,  INFINITY,  INFINITY};

        int cbase = chunk * 256;
        const unsigned short* bbase = ebf + (cbase >> 4) * 2048 + lane * 8;
        #pragma unroll 2
        for (int ct = 0; ct < 16; ++ct) {
            int col = cbase + ct * 16 + lm;
            const unsigned short* bp = bbase + ct * 2048;
            short8 b0 = *reinterpret_cast<const short8*>(bp);
            short8 b1 = *reinterpret_cast<const short8*>(bp + 512);
            short8 b2 = *reinterpret_cast<const short8*>(bp + 1024);
            short8 b3 = *reinterpret_cast<const short8*>(bp + 1536);
            f32x4 c = {0.f, 0.f, 0.f, 0.f};
            c = __builtin_amdgcn_mfma_f32_16x16x32_bf16(a0, b0, c, 0, 0, 0);
            c = __builtin_amdgcn_mfma_f32_16x16x32_bf16(a1, b1, c, 0, 0, 0);
            c = __builtin_amdgcn_mfma_f32_16x16x32_bf16(a2, b2, c, 0, 0, 0);
            c = __builtin_amdgcn_mfma_f32_16x16x32_bf16(a3, b3, c, 0, 0, 0);
            float sqc = sq[col];
            int lc = labels[col];
            float cmax = -INFINITY, cmin = INFINITY;
            #pragma unroll
            for (int r = 0; r < 4; ++r) {
                float v = fmaxf(fmaf(c[r], -2.0f, sqc) + sqr[r], 0.f);  // d^2 >= 0
                bool same = (lc == labr[r]);
                rmax[r] = same ? fmaxf(rmax[r], v) : rmax[r];
                rmin[r] = same ? rmin[r] : fminf(rmin[r], v);
                cmax    = same ? fmaxf(cmax, v) : cmax;
                cmin    = same ? cmin : fminf(cmin, v);
            }
            // fold this wave's 16 rows into the 16 cols (combine lq groups)
            cmax = fmaxf(cmax, __shfl_xor(cmax, 16, 64));
            cmax = fmaxf(cmax, __shfl_xor(cmax, 32, 64));
            cmin = fminf(cmin, __shfl_xor(cmin, 16, 64));
            cmin = fminf(cmin, __shfl_xor(cmin, 32, 64));
            if (lq == 0) {   // 16 lanes, 16 distinct banks -> conflict-free ds atomics
                atomicMax(&colk[ct * 16 + lm], enc_max(fmaxf(cmax, 0.f)));
                atomicMax(&colk[256 + ct * 16 + lm], enc_min(fmaxf(cmin, 0.f)));
            }
        }
        // row reduce across the 16 col-slots
        #pragma unroll
        for (int off = 1; off < 16; off <<= 1) {
            #pragma unroll
            for (int r = 0; r < 4; ++r) {
                rmax[r] = fmaxf(rmax[r], __shfl_xor(rmax[r], off, 64));
                rmin[r] = fminf(rmin[r], __shfl_xor(rmin[r], off, 64));
            }
        }
        if (lm == 0) {
            int row0 = rbase + lq * 4;
            #pragma unroll
            for (int r = 0; r < 4; ++r) {
                unsigned int kx = enc_max(fmaxf(rmax[r], 0.f));
                unsigned int kn = enc_min(fmaxf(rmin[r], 0.f));
                if (kx != ENC_MAX_ID)
                    __hip_atomic_fetch_max(&maxk[row0 + r], kx,
                                           __ATOMIC_RELAXED, __HIP_MEMORY_SCOPE_AGENT);
                if (kn != ENC_MIN_ID)
                    __hip_atomic_fetch_max(&mink[row0 + r], kn,
                                           __ATOMIC_RELAXED, __HIP_MEMORY_SCOPE_AGENT);
            }
        }
        __syncthreads();
        // column publish: one thread per col
        {
            unsigned int kx = colk[tid], kn = colk[256 + tid];
            int col = cbase + tid;
            if (kx > ENC_MAX_ID)       // >: skip identity AND the harmless enc_max(0)
                __hip_atomic_fetch_max(&maxk[col], kx,
                                       __ATOMIC_RELAXED, __HIP_MEMORY_SCOPE_AGENT);
            if (kn != 0 && kn != ENC_MIN_ID)
                __hip_atomic_fetch_max(&mink[col], kn,
                                       __ATOMIC_RELAXED, __HIP_MEMORY_SCOPE_AGENT);
        }
    } else {
        // ---------------- cross-entropy ----------------
        int R0 = (bid - NTILE) * 16;
        lg[tid >> 4][112 + (tid & 15)] = -INFINITY;   // pad cols 112..127

        const unsigned short* apt = ebf + (R0 >> 4) * 2048 + lane * 8;
        short8 a0 = *reinterpret_cast<const short8*>(apt);
        short8 a1 = *reinterpret_cast<const short8*>(apt + 512);
        short8 a2 = *reinterpret_cast<const short8*>(apt + 1024);
        short8 a3 = *reinterpret_cast<const short8*>(apt + 1536);

        for (int t = wave * 2; t < 7 && t < wave * 2 + 2; ++t) {
            int cls = t * 16 + lm;
            const unsigned short* bp = wbf + t * 2048 + lane * 8;
            short8 b0 = *reinterpret_cast<const short8*>(bp);
            short8 b1 = *reinterpret_cast<const short8*>(bp + 512);
            short8 b2 = *reinterpret_cast<const short8*>(bp + 1024);
            short8 b3 = *reinterpret_cast<const short8*>(bp + 1536);
            f32x4 c = {0.f, 0.f, 0.f, 0.f};
            c = __builtin_amdgcn_mfma_f32_16x16x32_bf16(a0, b0, c, 0, 0, 0);
            c = __builtin_amdgcn_mfma_f32_16x16x32_bf16(a1, b1, c, 0, 0, 0);
            c = __builtin_amdgcn_mfma_f32_16x16x32_bf16(a2, b2, c, 0, 0, 0);
            c = __builtin_amdgcn_mfma_f32_16x16x32_bf16(a3, b3, c, 0, 0, 0);
            float bias = (cls < NCLS) ? fcb[cls] : -INFINITY;
            #pragma unroll
            for (int r = 0; r < 4; ++r)
                lg[lq * 4 + r][t * 16 + lm] = c[r] + bias;
        }
        __syncthreads();
        float cacc = 0.f;
        #pragma unroll
        for (int i = 0; i < 4; ++i) {
            int r = wave * 4 + i;
            float x0 = lg[r][lane], x1 = lg[r][lane + 64];
            float m = fmaxf(x0, x1);
            #pragma unroll
            for (int off = 1; off < 64; off <<= 1) m = fmaxf(m, __shfl_xor(m, off, 64));
            float s = expf(x0 - m) + expf(x1 - m);    // -inf pads -> 0
            #pragma unroll
            for (int off = 1; off < 64; off <<= 1) s += __shfl_xor(s, off, 64);
            if (lane == 0) {
                int lab = labels[R0 + r];
                cacc += (m + logf(s)) - lg[r][lab];
            }
        }
        __syncthreads();
        if (lane == 0) lg[0][wave] = cacc;
        __syncthreads();
        if (tid == 0) {
            float bsum = lg[0][0] + lg[0][1] + lg[0][2] + lg[0][3];
            __hip_atomic_fetch_add(ce_sum, bsum,
                                   __ATOMIC_RELAXED, __HIP_MEMORY_SCOPE_AGENT);
        }
    }

    // ------- fence-free ticket fan-in -------
    __syncthreads();
    asm volatile("s_waitcnt vmcnt(0)" ::: "memory");
    if (tid == 0) {
        int old = __hip_atomic_fetch_add(ticket, 1,
                                         __ATOMIC_RELAXED, __HIP_MEMORY_SCOPE_AGENT);
        lastFlag = (old == GRID_MAIN - 1);
    }
    __syncthreads();
    if (lastFlag) {
        float acc = 0.f;
        #pragma unroll
        for (int rr = 0; rr < 16; ++rr) {
            int row = rr * 256 + tid;
            unsigned int kx = __hip_atomic_load(&maxk[row], __ATOMIC_RELAXED,
                                                __HIP_MEMORY_SCOPE_AGENT);
            unsigned int kn = __hip_atomic_load(&mink[row], __ATOMIC_RELAXED,
                                                __HIP_MEMORY_SCOPE_AGENT);
            float ap = sqrtf(fmaxf(dec_max(kx), 1e-12f));
            float an = sqrtf(fmaxf(dec_min(kn), 1e-12f));
            acc += fmaxf(ap - an + MARGIN, 0.f);
        }
        float* red = reinterpret_cast<float*>(lg);
        red[tid] = acc;
        __syncthreads();
        for (int s = 128; s > 0; s >>= 1) {
            if (tid < s) red[tid] += red[tid + s];
            __syncthreads();
        }
        if (tid == 0) {
            float ces = __hip_atomic_load(ce_sum, __ATOMIC_RELAXED,
                                          __HIP_MEMORY_SCOPE_AGENT);
            out[0] = (red[0] + ces) * (1.0f / BATCH);
        }
    }
}

extern "C" void kernel_launch(void* const* d_in, const int* in_sizes, int n_in,
                              void* d_out, int out_size, void* d_ws, size_t ws_size,
                              hipStream_t stream) {
    const float* emb    = (const float*)d_in[0];
    const int*   labels = (const int*)  d_in[1];
    const float* fcw    = (const float*)d_in[2];
    const float* fcb    = (const float*)d_in[3];
    float* out = (float*)d_out;

    char* ws = (char*)d_ws;
    unsigned short* ebf = (unsigned short*)(ws);                 // 1 MB (frag-major)
    unsigned short* wbf = (unsigned short*)(ws + 1048576);       // 28 KB (pad 32K)
    float* sq           = (float*)(ws + 1081344);                // 16 KB
    char* fan           = ws + 1097728;                          // zeroed by prep
    int*   ticket       = (int*)(fan);                           // 4 B
    float* ce_sum       = (float*)(fan + 4);                     // 4 B
    unsigned int* maxk  = (unsigned int*)(fan + 8);              // 16 KB
    unsigned int* mink  = (unsigned int*)(fan + 8 + 16384);      // 16 KB

    prep_kernel<<<258, 256, 0, stream>>>(emb, fcw, ebf, sq, wbf,
                                         (unsigned int*)fan);
    main_kernel<<<GRID_MAIN, 256, 0, stream>>>(ebf, wbf, sq, labels, fcb,
                                               maxk, mink, ce_sum, ticket, out);
}

// Round 10
// 94.107 us; speedup vs baseline: 1.1215x; 1.0135x over previous
//
#include <hip/hip_runtime.h>
#include <math.h>

#define BATCH 4096
#define DIM 128
#define NCLS 100
#define MARGIN 0.3f
#define NTILE 272          // upper-triangle 128x256 supertiles
#define GRID_MAIN 528      // 272 pairwise + 256 CE

typedef __attribute__((ext_vector_type(8))) short short8;
typedef __attribute__((ext_vector_type(4))) float f32x4;

// ---- bf16 helpers (bit-level, RNE) ----
__device__ __forceinline__ unsigned short f2bf(float f) {
    unsigned int u = __float_as_uint(f);
    unsigned int r = (u + 0x7FFFu + ((u >> 16) & 1u)) >> 16;
    return (unsigned short)r;
}
__device__ __forceinline__ float bf2f(unsigned short b) {
    return __uint_as_float(((unsigned int)b) << 16);
}

// Order-preserving encodings for NONNEGATIVE floats; identity = 0 under atomic max.
#define ENC_MAX_ID 0x80000000u   /* enc_max(0.0f) */
#define ENC_MIN_ID 0x403FFFFFu   /* enc_min(+inf) */
__device__ __forceinline__ unsigned int enc_max(float v) {
    return (__float_as_uint(v) >> 1) | 0x80000000u;
}
__device__ __forceinline__ float dec_max(unsigned int k) {
    return __uint_as_float((k & 0x7FFFFFFFu) << 1);
}
__device__ __forceinline__ unsigned int enc_min(float v) {
    return 0x7FFFFFFFu - (__float_as_uint(v) >> 1);
}
__device__ __forceinline__ float dec_min(unsigned int k) {
    return __uint_as_float((0x7FFFFFFFu - k) << 1);
}

// FRAGMENT-MAJOR layout: for 16-row group g, element (row%16, dim) lives at
// short-index g*2048 + (dim>>3)*128 + (row%16)*8 + (dim&7). Fragment read j
// for lane l is contiguous: g*2048 + j*512 + l*8 shorts = base + l*16 bytes.

// K1: blocks 0..255: emb->bf16 (frag-major) + sq (from rounded values).
//     blocks 256..257: fc_w->bf16 frag-major (padded to 112 classes) + zero fan-in.
__global__ __launch_bounds__(256) void prep_kernel(
        const float* __restrict__ emb, const float* __restrict__ fcw,
        unsigned short* __restrict__ ebf, float* __restrict__ sq,
        unsigned short* __restrict__ wbf, unsigned int* __restrict__ fanz) {
    int bid = blockIdx.x, tid = threadIdx.x;
    if (bid < 256) {
        int wave = tid >> 6, lane = tid & 63;
        unsigned int* dstg = reinterpret_cast<unsigned int*>(ebf) + bid * 1024;
        #pragma unroll
        for (int r = 0; r < 4; ++r) {
            int rowl = wave * 4 + r;                 // row within group (0..15)
            int row = bid * 16 + rowl;
            const float2* src = reinterpret_cast<const float2*>(emb + row * DIM);
            float2 xy = src[lane];                   // dims 2*lane, 2*lane+1
            unsigned short b0 = f2bf(xy.x), b1 = f2bf(xy.y);
            float y0 = bf2f(b0), y1 = bf2f(b1);
            dstg[(lane >> 2) * 64 + rowl * 4 + (lane & 3)] =
                ((unsigned int)b1 << 16) | (unsigned int)b0;
            float acc = y0 * y0 + y1 * y1;
            #pragma unroll
            for (int off = 1; off < 64; off <<= 1) acc += __shfl_xor(acc, off, 64);
            if (lane == 0) sq[row] = acc;
        }
    } else {
        int idx = (bid - 256) * 256 + tid;          // 512 threads total
        for (int k = idx; k < 112 * DIM; k += 512) {
            int cls = k >> 7, d = k & 127;
            int dst = (cls >> 4) * 2048 + (d >> 3) * 128 + (cls & 15) * 8 + (d & 7);
            wbf[dst] = (k < NCLS * DIM) ? f2bf(fcw[k]) : (unsigned short)0;
        }
        for (int w = idx; w < 8194; w += 512)       // ticket+ce_sum+maxk+mink
            fanz[w] = 0;
    }
}

// K2: blocks 0..271  -> upper-triangle 128x256 supertiles; each wave owns 32
//                       rows (2 MFMA row-groups, 2 independent MFMA chains/ct);
//     blocks 272..527 -> CE per 16 rows via MFMA logits + wave softmax.
//     Fence-free encoded-atomic fan-in; last block reduces + writes out[0].
__global__ __launch_bounds__(256) void main_kernel(
        const unsigned short* __restrict__ ebf, const unsigned short* __restrict__ wbf,
        const float* __restrict__ sq, const int* __restrict__ labels,
        const float* __restrict__ fcb,
        unsigned int* __restrict__ maxk, unsigned int* __restrict__ mink,
        float* __restrict__ ce_sum, int* __restrict__ ticket,
        float* __restrict__ out) {
    __shared__ float lg[16][128];
    __shared__ unsigned int colk[512];   // [0..255] col-max keys, [256..511] col-min keys
    __shared__ int lastFlag;
    int bid = blockIdx.x, tid = threadIdx.x;
    int wave = tid >> 6, lane = tid & 63;
    int lm = lane & 15, lq = lane >> 4;

    if (bid < NTILE) {
        // ---- map bid -> (rowgrp, chunk): chunk c admits rowgrps 0..2c+1 ----
        int c = 0, rem = bid;
        while (rem >= 2 * c + 2) { rem -= 2 * c + 2; ++c; }
        int rowgrp = rem;          // 0..2c+1 (128-row groups)
        int chunk  = c;            // 256-col chunks

        int rbase = rowgrp * 128 + wave * 32;   // this wave's 32 rows
        // A-frags: two 16-row groups, contiguous 4KB each, lane-coalesced
        const unsigned short* apt = ebf + (rbase >> 4) * 2048 + lane * 8;
        short8 a0 = *reinterpret_cast<const short8*>(apt);
        short8 a1 = *reinterpret_cast<const short8*>(apt + 512);
        short8 a2 = *reinterpret_cast<const short8*>(apt + 1024);
        short8 a3 = *reinterpret_cast<const short8*>(apt + 1536);
        short8 a4 = *reinterpret_cast<const short8*>(apt + 2048);
        short8 a5 = *reinterpret_cast<const short8*>(apt + 2560);
        short8 a6 = *reinterpret_cast<const short8*>(apt + 3072);
        short8 a7 = *reinterpret_cast<const short8*>(apt + 3584);

        int labr[8];
        float sqr[8];
        #pragma unroll
        for (int g = 0; g < 2; ++g)
            #pragma unroll
            for (int r = 0; r < 4; ++r) {
                labr[g * 4 + r] = labels[rbase + g * 16 + lq * 4 + r];
                sqr[g * 4 + r]  = sq[rbase + g * 16 + lq * 4 + r];
            }

        colk[tid] = 0; colk[256 + tid] = 0;
        __syncthreads();

        float rmax[8], rmin[8];
        #pragma unroll
        for (int r = 0; r < 8; ++r) { rmax[r] = -INFINITY; rmin[r] = INFINITY; }

        int cbase = chunk * 256;
        const unsigned short* bbase = ebf + (cbase >> 4) * 2048 + lane * 8;
        for (int ct = 0; ct < 16; ++ct) {
            int col = cbase + ct * 16 + lm;
            const unsigned short* bp = bbase + ct * 2048;
            short8 b0 = *reinterpret_cast<const short8*>(bp);
            short8 b1 = *reinterpret_cast<const short8*>(bp + 512);
            short8 b2 = *reinterpret_cast<const short8*>(bp + 1024);
            short8 b3 = *reinterpret_cast<const short8*>(bp + 1536);
            // two independent MFMA chains (row-groups 0 and 1)
            f32x4 c0 = {0.f, 0.f, 0.f, 0.f};
            f32x4 c1 = {0.f, 0.f, 0.f, 0.f};
            c0 = __builtin_amdgcn_mfma_f32_16x16x32_bf16(a0, b0, c0, 0, 0, 0);
            c1 = __builtin_amdgcn_mfma_f32_16x16x32_bf16(a4, b0, c1, 0, 0, 0);
            c0 = __builtin_amdgcn_mfma_f32_16x16x32_bf16(a1, b1, c0, 0, 0, 0);
            c1 = __builtin_amdgcn_mfma_f32_16x16x32_bf16(a5, b1, c1, 0, 0, 0);
            c0 = __builtin_amdgcn_mfma_f32_16x16x32_bf16(a2, b2, c0, 0, 0, 0);
            c1 = __builtin_amdgcn_mfma_f32_16x16x32_bf16(a6, b2, c1, 0, 0, 0);
            c0 = __builtin_amdgcn_mfma_f32_16x16x32_bf16(a3, b3, c0, 0, 0, 0);
            c1 = __builtin_amdgcn_mfma_f32_16x16x32_bf16(a7, b3, c1, 0, 0, 0);
            float sqc = sq[col];
            int lc = labels[col];
            float cmax = -INFINITY, cmin = INFINITY;
            #pragma unroll
            for (int r = 0; r < 4; ++r) {
                float v0 = fmaxf(fmaf(c0[r], -2.0f, sqc) + sqr[r], 0.f);
                bool s0 = (lc == labr[r]);
                rmax[r] = s0 ? fmaxf(rmax[r], v0) : rmax[r];
                rmin[r] = s0 ? rmin[r] : fminf(rmin[r], v0);
                cmax    = s0 ? fmaxf(cmax, v0) : cmax;
                cmin    = s0 ? cmin : fminf(cmin, v0);
                float v1 = fmaxf(fmaf(c1[r], -2.0f, sqc) + sqr[4 + r], 0.f);
                bool s1 = (lc == labr[4 + r]);
                rmax[4 + r] = s1 ? fmaxf(rmax[4 + r], v1) : rmax[4 + r];
                rmin[4 + r] = s1 ? rmin[4 + r] : fminf(rmin[4 + r], v1);
                cmax        = s1 ? fmaxf(cmax, v1) : cmax;
                cmin        = s1 ? cmin : fminf(cmin, v1);
            }
            // fold this wave's 32 rows into the 16 cols (combine lq groups)
            cmax = fmaxf(cmax, __shfl_xor(cmax, 16, 64));
            cmax = fmaxf(cmax, __shfl_xor(cmax, 32, 64));
            cmin = fminf(cmin, __shfl_xor(cmin, 16, 64));
            cmin = fminf(cmin, __shfl_xor(cmin, 32, 64));
            if (lq == 0) {   // 16 lanes, 16 distinct banks -> conflict-free ds atomics
                atomicMax(&colk[ct * 16 + lm], enc_max(fmaxf(cmax, 0.f)));
                atomicMax(&colk[256 + ct * 16 + lm], enc_min(fmaxf(cmin, 0.f)));
            }
        }
        // row reduce across the 16 col-slots
        #pragma unroll
        for (int off = 1; off < 16; off <<= 1) {
            #pragma unroll
            for (int r = 0; r < 8; ++r) {
                rmax[r] = fmaxf(rmax[r], __shfl_xor(rmax[r], off, 64));
                rmin[r] = fminf(rmin[r], __shfl_xor(rmin[r], off, 64));
            }
        }
        if (lm == 0) {
            #pragma unroll
            for (int g = 0; g < 2; ++g)
                #pragma unroll
                for (int r = 0; r < 4; ++r) {
                    int row = rbase + g * 16 + lq * 4 + r;
                    unsigned int kx = enc_max(fmaxf(rmax[g * 4 + r], 0.f));
                    unsigned int kn = enc_min(fmaxf(rmin[g * 4 + r], 0.f));
                    if (kx != ENC_MAX_ID)
                        __hip_atomic_fetch_max(&maxk[row], kx,
                                               __ATOMIC_RELAXED, __HIP_MEMORY_SCOPE_AGENT);
                    if (kn != ENC_MIN_ID)
                        __hip_atomic_fetch_max(&mink[row], kn,
                                               __ATOMIC_RELAXED, __HIP_MEMORY_SCOPE_AGENT);
                }
        }
        __syncthreads();
        // column publish: one thread per col
        {
            unsigned int kx = colk[tid], kn = colk[256 + tid];
            int col = cbase + tid;
            if (kx > ENC_MAX_ID)       // >: skip identity AND the harmless enc_max(0)
                __hip_atomic_fetch_max(&maxk[col], kx,
                                       __ATOMIC_RELAXED, __HIP_MEMORY_SCOPE_AGENT);
            if (kn != 0 && kn != ENC_MIN_ID)
                __hip_atomic_fetch_max(&mink[col], kn,
                                       __ATOMIC_RELAXED, __HIP_MEMORY_SCOPE_AGENT);
        }
    } else {
        // ---------------- cross-entropy ----------------
        int R0 = (bid - NTILE) * 16;
        lg[tid >> 4][112 + (tid & 15)] = -INFINITY;   // pad cols 112..127

        const unsigned short* apt = ebf + (R0 >> 4) * 2048 + lane * 8;
        short8 a0 = *reinterpret_cast<const short8*>(apt);
        short8 a1 = *reinterpret_cast<const short8*>(apt + 512);
        short8 a2 = *reinterpret_cast<const short8*>(apt + 1024);
        short8 a3 = *reinterpret_cast<const short8*>(apt + 1536);

        for (int t = wave * 2; t < 7 && t < wave * 2 + 2; ++t) {
            int cls = t * 16 + lm;
            const unsigned short* bp = wbf + t * 2048 + lane * 8;
            short8 b0 = *reinterpret_cast<const short8*>(bp);
            short8 b1 = *reinterpret_cast<const short8*>(bp + 512);
            short8 b2 = *reinterpret_cast<const short8*>(bp + 1024);
            short8 b3 = *reinterpret_cast<const short8*>(bp + 1536);
            f32x4 c = {0.f, 0.f, 0.f, 0.f};
            c = __builtin_amdgcn_mfma_f32_16x16x32_bf16(a0, b0, c, 0, 0, 0);
            c = __builtin_amdgcn_mfma_f32_16x16x32_bf16(a1, b1, c, 0, 0, 0);
            c = __builtin_amdgcn_mfma_f32_16x16x32_bf16(a2, b2, c, 0, 0, 0);
            c = __builtin_amdgcn_mfma_f32_16x16x32_bf16(a3, b3, c, 0, 0, 0);
            float bias = (cls < NCLS) ? fcb[cls] : -INFINITY;
            #pragma unroll
            for (int r = 0; r < 4; ++r)
                lg[lq * 4 + r][t * 16 + lm] = c[r] + bias;
        }
        __syncthreads();
        float cacc = 0.f;
        #pragma unroll
        for (int i = 0; i < 4; ++i) {
            int r = wave * 4 + i;
            float x0 = lg[r][lane], x1 = lg[r][lane + 64];
            float m = fmaxf(x0, x1);
            #pragma unroll
            for (int off = 1; off < 64; off <<= 1) m = fmaxf(m, __shfl_xor(m, off, 64));
            float s = expf(x0 - m) + expf(x1 - m);    // -inf pads -> 0
            #pragma unroll
            for (int off = 1; off < 64; off <<= 1) s += __shfl_xor(s, off, 64);
            if (lane == 0) {
                int lab = labels[R0 + r];
                cacc += (m + logf(s)) - lg[r][lab];
            }
        }
        __syncthreads();
        if (lane == 0) lg[0][wave] = cacc;
        __syncthreads();
        if (tid == 0) {
            float bsum = lg[0][0] + lg[0][1] + lg[0][2] + lg[0][3];
            __hip_atomic_fetch_add(ce_sum, bsum,
                                   __ATOMIC_RELAXED, __HIP_MEMORY_SCOPE_AGENT);
        }
    }

    // ------- fence-free ticket fan-in -------
    __syncthreads();
    asm volatile("s_waitcnt vmcnt(0)" ::: "memory");
    if (tid == 0) {
        int old = __hip_atomic_fetch_add(ticket, 1,
                                         __ATOMIC_RELAXED, __HIP_MEMORY_SCOPE_AGENT);
        lastFlag = (old == GRID_MAIN - 1);
    }
    __syncthreads();
    if (lastFlag) {
        float acc = 0.f;
        #pragma unroll
        for (int rr = 0; rr < 16; ++rr) {
            int row = rr * 256 + tid;
            unsigned int kx = __hip_atomic_load(&maxk[row], __ATOMIC_RELAXED,
                                                __HIP_MEMORY_SCOPE_AGENT);
            unsigned int kn = __hip_atomic_load(&mink[row], __ATOMIC_RELAXED,
                                                __HIP_MEMORY_SCOPE_AGENT);
            float ap = sqrtf(fmaxf(dec_max(kx), 1e-12f));
            float an = sqrtf(fmaxf(dec_min(kn), 1e-12f));
            acc += fmaxf(ap - an + MARGIN, 0.f);
        }
        float* red = reinterpret_cast<float*>(lg);
        red[tid] = acc;
        __syncthreads();
        for (int s = 128; s > 0; s >>= 1) {
            if (tid < s) red[tid] += red[tid + s];
            __syncthreads();
        }
        if (tid == 0) {
            float ces = __hip_atomic_load(ce_sum, __ATOMIC_RELAXED,
                                          __HIP_MEMORY_SCOPE_AGENT);
            out[0] = (red[0] + ces) * (1.0f / BATCH);
        }
    }
}

extern "C" void kernel_launch(void* const* d_in, const int* in_sizes, int n_in,
                              void* d_out, int out_size, void* d_ws, size_t ws_size,
                              hipStream_t stream) {
    const float* emb    = (const float*)d_in[0];
    const int*   labels = (const int*)  d_in[1];
    const float* fcw    = (const float*)d_in[2];
    const float* fcb    = (const float*)d_in[3];
    float* out = (float*)d_out;

    char* ws = (char*)d_ws;
    unsigned short* ebf = (unsigned short*)(ws);                 // 1 MB (frag-major)
    unsigned short* wbf = (unsigned short*)(ws + 1048576);       // 28 KB (pad 32K)
    float* sq           = (float*)(ws + 1081344);                // 16 KB
    char* fan           = ws + 1097728;                          // zeroed by prep
    int*   ticket       = (int*)(fan);                           // 4 B
    float* ce_sum       = (float*)(fan + 4);                     // 4 B
    unsigned int* maxk  = (unsigned int*)(fan + 8);              // 16 KB
    unsigned int* mink  = (unsigned int*)(fan + 8 + 16384);      // 16 KB

    prep_kernel<<<258, 256, 0, stream>>>(emb, fcw, ebf, sq, wbf,
                                         (unsigned int*)fan);
    main_kernel<<<GRID_MAIN, 256, 0, stream>>>(ebf, wbf, sq, labels, fcb,
                                               maxk, mink, ce_sum, ticket, out);
}

// Round 11
// 93.158 us; speedup vs baseline: 1.1329x; 1.0102x over previous
//
#include <hip/hip_runtime.h>
#include <math.h>

#define BATCH 4096
#define DIM 128
#define NCLS 100
#define MARGIN 0.3f
#define NTILE 272          // upper-triangle 128x256 supertiles
#define GRID_MAIN 528      // 272 pairwise + 256 CE

typedef __attribute__((ext_vector_type(8))) short short8;
typedef __attribute__((ext_vector_type(4))) float f32x4;

// ---- bf16 helpers (bit-level, RNE) ----
__device__ __forceinline__ unsigned short f2bf(float f) {
    unsigned int u = __float_as_uint(f);
    unsigned int r = (u + 0x7FFFu + ((u >> 16) & 1u)) >> 16;
    return (unsigned short)r;
}
__device__ __forceinline__ float bf2f(unsigned short b) {
    return __uint_as_float(((unsigned int)b) << 16);
}

// Order-preserving encodings for NONNEGATIVE floats; identity = 0 under atomic max.
#define ENC_MAX_ID 0x80000000u   /* enc_max(0.0f) */
#define ENC_MIN_ID 0x403FFFFFu   /* enc_min(+inf) */
__device__ __forceinline__ unsigned int enc_max(float v) {
    return (__float_as_uint(v) >> 1) | 0x80000000u;
}
__device__ __forceinline__ float dec_max(unsigned int k) {
    return __uint_as_float((k & 0x7FFFFFFFu) << 1);
}
__device__ __forceinline__ unsigned int enc_min(float v) {
    return 0x7FFFFFFFu - (__float_as_uint(v) >> 1);
}
__device__ __forceinline__ float dec_min(unsigned int k) {
    return __uint_as_float((0x7FFFFFFFu - k) << 1);
}

// FRAGMENT-MAJOR layout: for 16-row group g, element (row%16, dim) lives at
// short-index g*2048 + (dim>>3)*128 + (row%16)*8 + (dim&7). Fragment read j
// for lane l is contiguous: g*2048 + j*512 + l*8 shorts = base + l*16 bytes.

// K1: blocks 0..255: emb->bf16 (frag-major) + sq (from rounded values).
//     blocks 256..257: fc_w->bf16 frag-major (padded to 112 classes) + zero fan-in.
__global__ __launch_bounds__(256) void prep_kernel(
        const float* __restrict__ emb, const float* __restrict__ fcw,
        unsigned short* __restrict__ ebf, float* __restrict__ sq,
        unsigned short* __restrict__ wbf, unsigned int* __restrict__ fanz) {
    int bid = blockIdx.x, tid = threadIdx.x;
    if (bid < 256) {
        int wave = tid >> 6, lane = tid & 63;
        unsigned int* dstg = reinterpret_cast<unsigned int*>(ebf) + bid * 1024;
        #pragma unroll
        for (int r = 0; r < 4; ++r) {
            int rowl = wave * 4 + r;                 // row within group (0..15)
            int row = bid * 16 + rowl;
            const float2* src = reinterpret_cast<const float2*>(emb + row * DIM);
            float2 xy = src[lane];                   // dims 2*lane, 2*lane+1
            unsigned short b0 = f2bf(xy.x), b1 = f2bf(xy.y);
            float y0 = bf2f(b0), y1 = bf2f(b1);
            dstg[(lane >> 2) * 64 + rowl * 4 + (lane & 3)] =
                ((unsigned int)b1 << 16) | (unsigned int)b0;
            float acc = y0 * y0 + y1 * y1;
            #pragma unroll
            for (int off = 1; off < 64; off <<= 1) acc += __shfl_xor(acc, off, 64);
            if (lane == 0) sq[row] = acc;
        }
    } else {
        int idx = (bid - 256) * 256 + tid;          // 512 threads total
        for (int k = idx; k < 112 * DIM; k += 512) {
            int cls = k >> 7, d = k & 127;
            int dst = (cls >> 4) * 2048 + (d >> 3) * 128 + (cls & 15) * 8 + (d & 7);
            wbf[dst] = (k < NCLS * DIM) ? f2bf(fcw[k]) : (unsigned short)0;
        }
        for (int w = idx; w < 8194; w += 512)       // ticket+ce_sum+maxk+mink
            fanz[w] = 0;
    }
}

// K2: blocks 0..271  -> upper-triangle 128x256 supertiles, DOUBLE-BUFFERED LDS
//                       B-staging (block stages each 4KB B-tile ONCE; waves
//                       read fragments via ds_read_b128; global B-instrs /4);
//     blocks 272..527 -> CE per 16 rows via MFMA logits + wave softmax.
//     Fence-free encoded-atomic fan-in; last block reduces + writes out[0].
__global__ __launch_bounds__(256) void main_kernel(
        const unsigned short* __restrict__ ebf, const unsigned short* __restrict__ wbf,
        const float* __restrict__ sq, const int* __restrict__ labels,
        const float* __restrict__ fcb,
        unsigned int* __restrict__ maxk, unsigned int* __restrict__ mink,
        float* __restrict__ ce_sum, int* __restrict__ ticket,
        float* __restrict__ out) {
    __shared__ float lg[16][128];
    __shared__ unsigned int colk[512];   // [0..255] col-max keys, [256..511] col-min keys
    __shared__ unsigned short bstage[2][2048];   // 2 x 4KB B-tiles
    __shared__ int lastFlag;
    int bid = blockIdx.x, tid = threadIdx.x;
    int wave = tid >> 6, lane = tid & 63;
    int lm = lane & 15, lq = lane >> 4;

    if (bid < NTILE) {
        // ---- map bid -> (rowgrp, chunk): chunk c admits rowgrps 0..2c+1 ----
        int c = 0, rem = bid;
        while (rem >= 2 * c + 2) { rem -= 2 * c + 2; ++c; }
        int rowgrp = rem;          // 0..2c+1 (128-row groups)
        int chunk  = c;            // 256-col chunks

        int rbase = rowgrp * 128 + wave * 32;   // this wave's 32 rows
        // A-frags: two 16-row groups, contiguous 4KB each, lane-coalesced
        const unsigned short* apt = ebf + (rbase >> 4) * 2048 + lane * 8;
        short8 a0 = *reinterpret_cast<const short8*>(apt);
        short8 a1 = *reinterpret_cast<const short8*>(apt + 512);
        short8 a2 = *reinterpret_cast<const short8*>(apt + 1024);
        short8 a3 = *reinterpret_cast<const short8*>(apt + 1536);
        short8 a4 = *reinterpret_cast<const short8*>(apt + 2048);
        short8 a5 = *reinterpret_cast<const short8*>(apt + 2560);
        short8 a6 = *reinterpret_cast<const short8*>(apt + 3072);
        short8 a7 = *reinterpret_cast<const short8*>(apt + 3584);

        int labr[8];
        float sqr[8];
        #pragma unroll
        for (int g = 0; g < 2; ++g)
            #pragma unroll
            for (int r = 0; r < 4; ++r) {
                labr[g * 4 + r] = labels[rbase + g * 16 + lq * 4 + r];
                sqr[g * 4 + r]  = sq[rbase + g * 16 + lq * 4 + r];
            }

        colk[tid] = 0; colk[256 + tid] = 0;

        float rmax[8], rmin[8];
        #pragma unroll
        for (int r = 0; r < 8; ++r) { rmax[r] = -INFINITY; rmin[r] = INFINITY; }

        int cbase = chunk * 256;
        // B-tile ct occupies shorts [ct*2048, (ct+1)*2048) of the chunk's region.
        // This wave stages quarter `wave`: 64 lanes x 16B = 1024B.
        const unsigned short* btile = ebf + (cbase >> 4) * 2048 + wave * 512 + lane * 8;
        uint4 breg = *reinterpret_cast<const uint4*>(btile);   // tile 0

        for (int ct = 0; ct < 16; ++ct) {
            // write tile ct to LDS buffer, prefetch tile ct+1 into regs
            *reinterpret_cast<uint4*>(&bstage[ct & 1][wave * 512 + lane * 8]) = breg;
            if (ct < 15)
                breg = *reinterpret_cast<const uint4*>(btile + (ct + 1) * 2048);
            __syncthreads();   // also covers colk init on ct=0

            const unsigned short* bb = &bstage[ct & 1][lane * 8];
            short8 b0 = *reinterpret_cast<const short8*>(bb);
            short8 b1 = *reinterpret_cast<const short8*>(bb + 512);
            short8 b2 = *reinterpret_cast<const short8*>(bb + 1024);
            short8 b3 = *reinterpret_cast<const short8*>(bb + 1536);
            // two independent MFMA chains (row-groups 0 and 1)
            f32x4 c0 = {0.f, 0.f, 0.f, 0.f};
            f32x4 c1 = {0.f, 0.f, 0.f, 0.f};
            c0 = __builtin_amdgcn_mfma_f32_16x16x32_bf16(a0, b0, c0, 0, 0, 0);
            c1 = __builtin_amdgcn_mfma_f32_16x16x32_bf16(a4, b0, c1, 0, 0, 0);
            c0 = __builtin_amdgcn_mfma_f32_16x16x32_bf16(a1, b1, c0, 0, 0, 0);
            c1 = __builtin_amdgcn_mfma_f32_16x16x32_bf16(a5, b1, c1, 0, 0, 0);
            c0 = __builtin_amdgcn_mfma_f32_16x16x32_bf16(a2, b2, c0, 0, 0, 0);
            c1 = __builtin_amdgcn_mfma_f32_16x16x32_bf16(a6, b2, c1, 0, 0, 0);
            c0 = __builtin_amdgcn_mfma_f32_16x16x32_bf16(a3, b3, c0, 0, 0, 0);
            c1 = __builtin_amdgcn_mfma_f32_16x16x32_bf16(a7, b3, c1, 0, 0, 0);

            int col = cbase + ct * 16 + lm;
            float sqc = sq[col];
            int lc = labels[col];
            float cmax = -INFINITY, cmin = INFINITY;
            #pragma unroll
            for (int r = 0; r < 4; ++r) {
                float v0 = fmaxf(fmaf(c0[r], -2.0f, sqc) + sqr[r], 0.f);
                bool s0 = (lc == labr[r]);
                rmax[r] = s0 ? fmaxf(rmax[r], v0) : rmax[r];
                rmin[r] = s0 ? rmin[r] : fminf(rmin[r], v0);
                cmax    = s0 ? fmaxf(cmax, v0) : cmax;
                cmin    = s0 ? cmin : fminf(cmin, v0);
                float v1 = fmaxf(fmaf(c1[r], -2.0f, sqc) + sqr[4 + r], 0.f);
                bool s1 = (lc == labr[4 + r]);
                rmax[4 + r] = s1 ? fmaxf(rmax[4 + r], v1) : rmax[4 + r];
                rmin[4 + r] = s1 ? rmin[4 + r] : fminf(rmin[4 + r], v1);
                cmax        = s1 ? fmaxf(cmax, v1) : cmax;
                cmin        = s1 ? cmin : fminf(cmin, v1);
            }
            // fold this wave's 32 rows into the 16 cols (combine lq groups)
            cmax = fmaxf(cmax, __shfl_xor(cmax, 16, 64));
            cmax = fmaxf(cmax, __shfl_xor(cmax, 32, 64));
            cmin = fminf(cmin, __shfl_xor(cmin, 16, 64));
            cmin = fminf(cmin, __shfl_xor(cmin, 32, 64));
            if (lq == 0) {   // 16 lanes, 16 distinct banks -> conflict-free ds atomics
                atomicMax(&colk[ct * 16 + lm], enc_max(fmaxf(cmax, 0.f)));
                atomicMax(&colk[256 + ct * 16 + lm], enc_min(fmaxf(cmin, 0.f)));
            }
        }
        // row reduce across the 16 col-slots
        #pragma unroll
        for (int off = 1; off < 16; off <<= 1) {
            #pragma unroll
            for (int r = 0; r < 8; ++r) {
                rmax[r] = fmaxf(rmax[r], __shfl_xor(rmax[r], off, 64));
                rmin[r] = fminf(rmin[r], __shfl_xor(rmin[r], off, 64));
            }
        }
        if (lm == 0) {
            #pragma unroll
            for (int g = 0; g < 2; ++g)
                #pragma unroll
                for (int r = 0; r < 4; ++r) {
                    int row = rbase + g * 16 + lq * 4 + r;
                    unsigned int kx = enc_max(fmaxf(rmax[g * 4 + r], 0.f));
                    unsigned int kn = enc_min(fmaxf(rmin[g * 4 + r], 0.f));
                    if (kx != ENC_MAX_ID)
                        __hip_atomic_fetch_max(&maxk[row], kx,
                                               __ATOMIC_RELAXED, __HIP_MEMORY_SCOPE_AGENT);
                    if (kn != ENC_MIN_ID)
                        __hip_atomic_fetch_max(&mink[row], kn,
                                               __ATOMIC_RELAXED, __HIP_MEMORY_SCOPE_AGENT);
                }
        }
        __syncthreads();
        // column publish: one thread per col
        {
            unsigned int kx = colk[tid], kn = colk[256 + tid];
            int col = cbase + tid;
            if (kx > ENC_MAX_ID)       // >: skip identity AND the harmless enc_max(0)
                __hip_atomic_fetch_max(&maxk[col], kx,
                                       __ATOMIC_RELAXED, __HIP_MEMORY_SCOPE_AGENT);
            if (kn != 0 && kn != ENC_MIN_ID)
                __hip_atomic_fetch_max(&mink[col], kn,
                                       __ATOMIC_RELAXED, __HIP_MEMORY_SCOPE_AGENT);
        }
    } else {
        // ---------------- cross-entropy ----------------
        int R0 = (bid - NTILE) * 16;
        lg[tid >> 4][112 + (tid & 15)] = -INFINITY;   // pad cols 112..127

        const unsigned short* apt = ebf + (R0 >> 4) * 2048 + lane * 8;
        short8 a0 = *reinterpret_cast<const short8*>(apt);
        short8 a1 = *reinterpret_cast<const short8*>(apt + 512);
        short8 a2 = *reinterpret_cast<const short8*>(apt + 1024);
        short8 a3 = *reinterpret_cast<const short8*>(apt + 1536);

        for (int t = wave * 2; t < 7 && t < wave * 2 + 2; ++t) {
            int cls = t * 16 + lm;
            const unsigned short* bp = wbf + t * 2048 + lane * 8;
            short8 b0 = *reinterpret_cast<const short8*>(bp);
            short8 b1 = *reinterpret_cast<const short8*>(bp + 512);
            short8 b2 = *reinterpret_cast<const short8*>(bp + 1024);
            short8 b3 = *reinterpret_cast<const short8*>(bp + 1536);
            f32x4 c = {0.f, 0.f, 0.f, 0.f};
            c = __builtin_amdgcn_mfma_f32_16x16x32_bf16(a0, b0, c, 0, 0, 0);
            c = __builtin_amdgcn_mfma_f32_16x16x32_bf16(a1, b1, c, 0, 0, 0);
            c = __builtin_amdgcn_mfma_f32_16x16x32_bf16(a2, b2, c, 0, 0, 0);
            c = __builtin_amdgcn_mfma_f32_16x16x32_bf16(a3, b3, c, 0, 0, 0);
            float bias = (cls < NCLS) ? fcb[cls] : -INFINITY;
            #pragma unroll
            for (int r = 0; r < 4; ++r)
                lg[lq * 4 + r][t * 16 + lm] = c[r] + bias;
        }
        __syncthreads();
        float cacc = 0.f;
        #pragma unroll
        for (int i = 0; i < 4; ++i) {
            int r = wave * 4 + i;
            float x0 = lg[r][lane], x1 = lg[r][lane + 64];
            float m = fmaxf(x0, x1);
            #pragma unroll
            for (int off = 1; off < 64; off <<= 1) m = fmaxf(m, __shfl_xor(m, off, 64));
            float s = expf(x0 - m) + expf(x1 - m);    // -inf pads -> 0
            #pragma unroll
            for (int off = 1; off < 64; off <<= 1) s += __shfl_xor(s, off, 64);
            if (lane == 0) {
                int lab = labels[R0 + r];
                cacc += (m + logf(s)) - lg[r][lab];
            }
        }
        __syncthreads();
        if (lane == 0) lg[0][wave] = cacc;
        __syncthreads();
        if (tid == 0) {
            float bsum = lg[0][0] + lg[0][1] + lg[0][2] + lg[0][3];
            __hip_atomic_fetch_add(ce_sum, bsum,
                                   __ATOMIC_RELAXED, __HIP_MEMORY_SCOPE_AGENT);
        }
    }

    // ------- fence-free ticket fan-in -------
    __syncthreads();
    asm volatile("s_waitcnt vmcnt(0)" ::: "memory");
    if (tid == 0) {
        int old = __hip_atomic_fetch_add(ticket, 1,
                                         __ATOMIC_RELAXED, __HIP_MEMORY_SCOPE_AGENT);
        lastFlag = (old == GRID_MAIN - 1);
    }
    __syncthreads();
    if (lastFlag) {
        float acc = 0.f;
        #pragma unroll
        for (int rr = 0; rr < 16; ++rr) {
            int row = rr * 256 + tid;
            unsigned int kx = __hip_atomic_load(&maxk[row], __ATOMIC_RELAXED,
                                                __HIP_MEMORY_SCOPE_AGENT);
            unsigned int kn = __hip_atomic_load(&mink[row], __ATOMIC_RELAXED,
                                                __HIP_MEMORY_SCOPE_AGENT);
            float ap = sqrtf(fmaxf(dec_max(kx), 1e-12f));
            float an = sqrtf(fmaxf(dec_min(kn), 1e-12f));
            acc += fmaxf(ap - an + MARGIN, 0.f);
        }
        float* red = reinterpret_cast<float*>(lg);
        red[tid] = acc;
        __syncthreads();
        for (int s = 128; s > 0; s >>= 1) {
            if (tid < s) red[tid] += red[tid + s];
            __syncthreads();
        }
        if (tid == 0) {
            float ces = __hip_atomic_load(ce_sum, __ATOMIC_RELAXED,
                                          __HIP_MEMORY_SCOPE_AGENT);
            out[0] = (red[0] + ces) * (1.0f / BATCH);
        }
    }
}

extern "C" void kernel_launch(void* const* d_in, const int* in_sizes, int n_in,
                              void* d_out, int out_size, void* d_ws, size_t ws_size,
                              hipStream_t stream) {
    const float* emb    = (const float*)d_in[0];
    const int*   labels = (const int*)  d_in[1];
    const float* fcw    = (const float*)d_in[2];
    const float* fcb    = (const float*)d_in[3];
    float* out = (float*)d_out;

    char* ws = (char*)d_ws;
    unsigned short* ebf = (unsigned short*)(ws);                 // 1 MB (frag-major)
    unsigned short* wbf = (unsigned short*)(ws + 1048576);       // 28 KB (pad 32K)
    float* sq           = (float*)(ws + 1081344);                // 16 KB
    char* fan           = ws + 1097728;                          // zeroed by prep
    int*   ticket       = (int*)(fan);                           // 4 B
    float* ce_sum       = (float*)(fan + 4);                     // 4 B
    unsigned int* maxk  = (unsigned int*)(fan + 8);              // 16 KB
    unsigned int* mink  = (unsigned int*)(fan + 8 + 16384);      // 16 KB

    prep_kernel<<<258, 256, 0, stream>>>(emb, fcw, ebf, sq, wbf,
                                         (unsigned int*)fan);
    main_kernel<<<GRID_MAIN, 256, 0, stream>>>(ebf, wbf, sq, labels, fcb,
                                               maxk, mink, ce_sum, ticket, out);
}